// Round 1
// baseline (1070.182 us; speedup 1.0000x reference)
//
#include <hip/hip_runtime.h>
#include <hip/hip_bf16.h>

typedef __attribute__((ext_vector_type(8))) short short8;
typedef __attribute__((ext_vector_type(4))) float floatx4;
typedef unsigned short u16;
typedef unsigned int u32;

#define BATCH 16
#define HH 224
#define WW 224
#define ICN 64
#define OCN 128
#define HP 226
#define WP 226

// conv tile: 2 output rows x 40 cols; block walks 6 w-chunks (last overlaps, stores idempotent)
#define MT 80
#define AR 168            // 4 padded input rows x 42 padded cols
#define AQ (AR*8)         // 1344 16-B chunks
#define A_BYTES (AR*128)  // 21504
#define NTILE 6

#define XB_BYTES ((size_t)BATCH*HP*WP*ICN*2)   // 104,603,648
#define WB_BYTES ((size_t)OCN*ICN*9*2)         // 147,456

// async global->LDS, 16B per lane; LDS dest = wave-uniform base + lane*16
#define ASYNC16(g, l) __builtin_amdgcn_global_load_lds( \
    (const __attribute__((address_space(1))) void*)(g), \
    (__attribute__((address_space(3))) void*)(l), 16, 0, 0)

__device__ __forceinline__ u16 f2bf(float f) {
  __hip_bfloat16 h = __float2bfloat16(f);
  return *reinterpret_cast<u16*>(&h);
}

__device__ __forceinline__ float fast_tanh(float x) {
  float e = __expf(2.0f * x);    // x>>0 -> 1, x<<0 -> -1, inf-safe
  return 1.0f - 2.0f / (e + 1.0f);
}

// ---------- detect_kernel: one wave decides container dtype, writes flag ----------
__global__ void detect_kernel(const u32* __restrict__ xw, u32* __restrict__ flag) {
  if (threadIdx.x == 0) {
    int cnt = 0;
    #pragma unroll 8
    for (int i = 0; i < 64; ++i) {
      u32 w = xw[i];
      int e0 = (w >> 7) & 0xFF;
      int e1 = (w >> 23) & 0xFF;
      cnt += (e0 >= 90 && e0 <= 160) ? 1 : 0;
      cnt += (e1 >= 90 && e1 <= 160) ? 1 : 0;
    }
    *flag = (cnt >= 120) ? 1u : 0u;
  }
}

// ---------- prep_x: NCHW (fp32 or bf16) -> zero-padded NHWC bf16 [b][226][226][64] ----------
__global__ __launch_bounds__(256) void prep_x(const void* __restrict__ xv, u16* __restrict__ xb,
                                              const u32* __restrict__ flag) {
  __shared__ u32 tile32[2][64*33];   // [w_local][ic_pair], stride 33
  const bool isbf = (*flag != 0u);
  const int tid = threadIdx.x;
  int bid = blockIdx.x;
  const int chunk = bid & 3;         // 4 chunks of 64 input cols
  int rest = bid >> 2;
  const int hp0 = rest % 113;        // rows hp0 and hp0+113
  const int b = rest / 113;
  const int wt = chunk * 64;
  const int icp = tid >> 3;          // ic pair 0..31
  const int oct = tid & 7;           // w octet 0..7
  const int w = wt + oct*8;
  const int ic0 = icp*2;

  #pragma unroll
  for (int t = 0; t < 2; ++t) {
    const int hp = hp0 + t*113;
    const int h = hp - 1;
    const bool valid = (h >= 0) && (h < HH) && (w < WW);
    const size_t b0 = (((size_t)(b*ICN + ic0))*HH + h)*WW + w;
    const size_t b1 = (((size_t)(b*ICN + ic0+1))*HH + h)*WW + w;
    u16 a[8], c[8];
    if (isbf) {
      short8 v0 = {0,0,0,0,0,0,0,0}, v1 = {0,0,0,0,0,0,0,0};
      if (valid) {
        v0 = *(const short8*)((const u16*)xv + b0);
        v1 = *(const short8*)((const u16*)xv + b1);
      }
      #pragma unroll
      for (int s = 0; s < 8; ++s) { a[s] = (u16)v0[s]; c[s] = (u16)v1[s]; }
    } else {
      floatx4 f0={0,0,0,0}, f1={0,0,0,0}, f2={0,0,0,0}, f3={0,0,0,0};
      if (valid) {
        const float* p0 = (const float*)xv + b0;
        const float* p1 = (const float*)xv + b1;
        f0 = *(const floatx4*)p0; f1 = *(const floatx4*)(p0+4);
        f2 = *(const floatx4*)p1; f3 = *(const floatx4*)(p1+4);
      }
      #pragma unroll
      for (int s = 0; s < 4; ++s) {
        a[s] = f2bf(f0[s]); a[4+s] = f2bf(f1[s]);
        c[s] = f2bf(f2[s]); c[4+s] = f2bf(f3[s]);
      }
    }
    #pragma unroll
    for (int s = 0; s < 8; ++s)
      tile32[t][(oct*8 + s)*33 + icp] = (u32)a[s] | ((u32)c[s] << 16);
  }
  __syncthreads();
  #pragma unroll
  for (int t = 0; t < 2; ++t) {
    const int hp = hp0 + t*113;
    #pragma unroll
    for (int p = 0; p < 2; ++p) {
      int idx = p*256 + tid;
      int wl = idx >> 3;
      int icc = idx & 7;
      int wp = wt + 1 + wl;
      if (wp < WP) {
        u32 cc[4];
        #pragma unroll
        for (int j = 0; j < 4; ++j) cc[j] = tile32[t][wl*33 + icc*4 + j];
        short8 o;
        #pragma unroll
        for (int j = 0; j < 4; ++j) { o[2*j] = (short)(cc[j] & 0xFFFF); o[2*j+1] = (short)(cc[j] >> 16); }
        *(short8*)(xb + (((size_t)(b*HP) + hp)*WP + wp)*ICN + icc*8) = o;
      }
    }
    if (chunk == 0 && tid < 8) {     // left border column wp=0
      short8 z = {0,0,0,0,0,0,0,0};
      *(short8*)(xb + (((size_t)(b*HP) + hp)*WP)*ICN + tid*8) = z;
    }
  }
}

// ---------- prep_w: OIHW (fp32 or bf16) -> [oc][tap*64+ic] bf16 ----------
__global__ __launch_bounds__(256) void prep_w(const void* __restrict__ wv_, u16* __restrict__ wb,
                                              const u32* __restrict__ flag) {
  const bool isbf = (*flag != 0u);
  int o = blockIdx.x*256 + threadIdx.x;   // 0..73727
  int oc = o / 576;
  int k = o - oc*576;
  int tap = k >> 6;
  int ic = k & 63;
  int src = oc*576 + ic*9 + tap;
  wb[o] = isbf ? ((const u16*)wv_)[src] : f2bf(((const float*)wv_)[src]);
}

// ---------- fused conv3x3 + bias + min_oc + double tanh ----------
// Persistent block per (b, h-pair) walking 6 w-chunks. A double-buffered in LDS,
// staged via global_load_lds issued one full tile ahead (latency hidden under the
// 180-MFMA compute + epilogue of the current tile). XOR swizzle preserved by
// pre-swizzling the per-lane GLOBAL source (involution), LDS dest stays linear.
// B is tile-invariant: tap prefetch wraps 8->0 so B is never cold across tiles.
__global__ __launch_bounds__(256, 3) void conv_min_kernel(
    const u16* __restrict__ xb, const u16* __restrict__ wb,
    const void* __restrict__ biasv, void* __restrict__ outv,
    const u32* __restrict__ flag)
{
  __shared__ __align__(16) char ldsA[2][A_BYTES];   // double-buffered A tile
  __shared__ float minbuf[4*MT];                    // dedicated (no aliasing hazards)

  const bool isbf = (*flag != 0u);
  const int tid = threadIdx.x;
  const int wv = tid >> 6;
  const int lane = tid & 63;
  const int m15 = lane & 15;
  const int quad = lane >> 4;

  // bijective XCD swizzle: 1792 blocks = 8 XCDs x 224 -> each XCD gets 2 full
  // batches' worth of contiguous h-pairs (boundary-row L2 reuse).
  int bid0 = blockIdx.x;
  int bid = (bid0 & 7) * 224 + (bid0 >> 3);
  const int h0 = (bid % 112) * 2;
  const int b = bid / 112;

  // ---- per-lane A-row bases: pixel p = mb*16 + m15 -> base = (p/40)*42 + p%40
  int arow[5];
  #pragma unroll
  for (int mb = 0; mb < 5; ++mb) {
    int p = mb*16 + m15;
    int ro = p / 40;
    arow[mb] = ro*42 + (p - ro*40);
  }

  // ---- per-lane staging source offsets (bytes), tile-invariant part.
  // chunk q = it*256 + tid: r=q>>3, slot=q&7, source chunk c = slot^(r&7)
  // (involution: LDS slot s of row r must hold global chunk s^(r&7))
  int offv[6];
  #pragma unroll
  for (int it = 0; it < 6; ++it) {
    int q = it*256 + tid;
    int r = q >> 3;
    int slot = q & 7;
    int c = slot ^ (r & 7);
    int dyi = (r * 781) >> 15;       // r/42, exact for r < 168 (tail lanes guarded)
    int wloc = r - dyi*42;
    offv[it] = ((dyi*WP + wloc)*ICN + c*8) * 2;
  }

  const char* xrow_b = (const char*)xb + 2*(((size_t)(b*HP) + h0)*WP*ICN);
  const u16* bbase = wb + (wv*32 + m15)*576 + quad*8;

  float bv0, bv1;
  if (isbf) {
    bv0 = __bfloat162float(((const __hip_bfloat16*)biasv)[wv*32 + m15]);
    bv1 = __bfloat162float(((const __hip_bfloat16*)biasv)[wv*32 + 16 + m15]);
  } else {
    bv0 = ((const float*)biasv)[wv*32 + m15];
    bv1 = ((const float*)biasv)[wv*32 + 16 + m15];
  }

  // ---- prologue: stage tile 0 (w0=0), preload B for tap 0
  #pragma unroll
  for (int it = 0; it < 6; ++it) {
    if (it < 5 || wv == 0) {   // tail iteration covers q=1280..1343 (wave 0 only)
      ASYNC16(xrow_b + offv[it], (char*)ldsA[0] + it*4096 + wv*1024);
    }
  }
  short8 bcur[2][2];
  #pragma unroll
  for (int nb = 0; nb < 2; ++nb)
    #pragma unroll
    for (int ks = 0; ks < 2; ++ks)
      bcur[nb][ks] = *(const short8*)(bbase + nb*16*576 + ks*32);

  __syncthreads();   // compiler drains vmcnt -> tile 0 resident

  int cur = 0;
  #pragma unroll 1
  for (int t = 0; t < NTILE; ++t) {
    const char* Abuf = (const char*)ldsA[cur];

    // issue next tile's staging NOW; it completes under this tile's compute+epilogue
    if (t + 1 < NTILE) {
      const int w0n = (t+1 < 5) ? (t+1)*40 : 184;
      const char* srcb = xrow_b + (size_t)w0n*128;
      char* dstb = (char*)ldsA[cur ^ 1];
      #pragma unroll
      for (int it = 0; it < 6; ++it) {
        if (it < 5 || wv == 0) {
          ASYNC16(srcb + offv[it], dstb + it*4096 + wv*1024);
        }
      }
    }
    __builtin_amdgcn_sched_barrier(0);   // pin stage issues before compute

    floatx4 acc[5][2];
    #pragma unroll
    for (int mb = 0; mb < 5; ++mb) {
      acc[mb][0] = (floatx4){0.f,0.f,0.f,0.f};
      acc[mb][1] = (floatx4){0.f,0.f,0.f,0.f};
    }

    #pragma unroll
    for (int tap = 0; tap < 9; ++tap) {
      short8 bnxt[2][2];
      const int tnx = (tap < 8) ? (tap + 1) : 0;   // wrap: keeps B hot across tiles
      #pragma unroll
      for (int nb = 0; nb < 2; ++nb)
        #pragma unroll
        for (int ks = 0; ks < 2; ++ks)
          bnxt[nb][ks] = *(const short8*)(bbase + nb*16*576 + tnx*64 + ks*32);
      const int dy = tap / 3;
      const int dx = tap - dy*3;
      const int rdelta = dy*42 + dx;
      #pragma unroll
      for (int ks = 0; ks < 2; ++ks) {
        const int csel = ks*4 + quad;
        short8 af[5];
        #pragma unroll
        for (int mb = 0; mb < 5; ++mb) {
          int row = arow[mb] + rdelta;
          af[mb] = *(const short8*)(Abuf + row*128 + ((csel ^ (row & 7))*16));
        }
        #pragma unroll
        for (int mb = 0; mb < 5; ++mb) {
          acc[mb][0] = __builtin_amdgcn_mfma_f32_16x16x32_bf16(af[mb], bcur[0][ks], acc[mb][0], 0, 0, 0);
          acc[mb][1] = __builtin_amdgcn_mfma_f32_16x16x32_bf16(af[mb], bcur[1][ks], acc[mb][1], 0, 0, 0);
        }
      }
      #pragma unroll
      for (int nb = 0; nb < 2; ++nb)
        #pragma unroll
        for (int ks = 0; ks < 2; ++ks)
          bcur[nb][ks] = bnxt[nb][ks];
    }

    // ---- epilogue (staged loads for t+1 still in flight underneath)
    const int w0 = (t < 5) ? t*40 : 184;
    #pragma unroll
    for (int mb = 0; mb < 5; ++mb) {
      #pragma unroll
      for (int r = 0; r < 4; ++r) {
        float v = fminf(acc[mb][0][r] + bv0, acc[mb][1][r] + bv1);
        v = fminf(v, __shfl_xor(v, 1));
        v = fminf(v, __shfl_xor(v, 2));
        v = fminf(v, __shfl_xor(v, 4));
        v = fminf(v, __shfl_xor(v, 8));
        if (m15 == 0)
          minbuf[wv*MT + mb*16 + quad*4 + r] = v;   // pixel = mb*16 + quad*4 + r
      }
    }
    __syncthreads();
    if (tid < MT) {
      float v = fminf(fminf(minbuf[tid], minbuf[MT + tid]),
                      fminf(minbuf[2*MT + tid], minbuf[3*MT + tid]));
      float tt = fast_tanh(fast_tanh(v));
      int ro = tid / 40;
      int co = tid - ro*40;
      size_t oi = ((size_t)(b*HH + h0 + ro))*WW + w0 + co;
      if (isbf) ((__hip_bfloat16*)outv)[oi] = __float2bfloat16(tt);
      else      ((float*)outv)[oi] = tt;
    }
    __syncthreads();   // minbuf reads done + next tile's A resident (vmcnt drained)
    cur ^= 1;
  }
}

extern "C" void kernel_launch(void* const* d_in, const int* in_sizes, int n_in,
                              void* d_out, int out_size, void* d_ws, size_t ws_size,
                              hipStream_t stream) {
  (void)in_sizes; (void)n_in; (void)out_size;
  if (ws_size < XB_BYTES + WB_BYTES + 16) return;

  const void* x  = d_in[0];
  const void* w  = d_in[1];
  const void* bias = d_in[2];
  u16* xb = (u16*)d_ws;
  u16* wb = (u16*)((char*)d_ws + XB_BYTES);
  u32* flag = (u32*)((char*)d_ws + XB_BYTES + WB_BYTES);

  detect_kernel<<<1, 64, 0, stream>>>((const u32*)x, flag);
  prep_x<<<BATCH*113*4, 256, 0, stream>>>(x, xb, flag);
  prep_w<<<288, 256, 0, stream>>>(w, wb, flag);
  conv_min_kernel<<<BATCH*112, 256, 0, stream>>>(xb, wb, bias, d_out, flag);
}

// Round 2
// 509.451 us; speedup vs baseline: 2.1007x; 2.1007x over previous
//
#include <hip/hip_runtime.h>
#include <hip/hip_bf16.h>

typedef __attribute__((ext_vector_type(8))) short short8;
typedef __attribute__((ext_vector_type(4))) float floatx4;
typedef unsigned short u16;
typedef unsigned int u32;

#define BATCH 16
#define HH 224
#define WW 224
#define ICN 64
#define OCN 128
#define HP 226
#define WP 226

// conv tile: 2 output rows x 40 cols per WG (6 w-chunks; last overlaps, stores idempotent)
#define MT 80
#define AR 168            // 4 padded input rows x 42 padded cols
#define AQ (AR*8)         // 1344 16-B chunks
#define A_BYTES (AR*128)  // 21504

#define XB_BYTES ((size_t)BATCH*HP*WP*ICN*2)   // 104,603,648
#define WB_BYTES ((size_t)OCN*ICN*9*2)         // 147,456

// async global->LDS, 16B per lane; LDS dest = wave-uniform base + lane*16
#define ASYNC16(g, l) __builtin_amdgcn_global_load_lds( \
    (const __attribute__((address_space(1))) void*)(g), \
    (__attribute__((address_space(3))) void*)(l), 16, 0, 0)

__device__ __forceinline__ u16 f2bf(float f) {
  __hip_bfloat16 h = __float2bfloat16(f);
  return *reinterpret_cast<u16*>(&h);
}

__device__ __forceinline__ float fast_tanh(float x) {
  float e = __expf(2.0f * x);    // x>>0 -> 1, x<<0 -> -1, inf-safe
  return 1.0f - 2.0f / (e + 1.0f);
}

// ---------- detect_kernel: one wave decides container dtype, writes flag ----------
__global__ void detect_kernel(const u32* __restrict__ xw, u32* __restrict__ flag) {
  if (threadIdx.x == 0) {
    int cnt = 0;
    #pragma unroll 8
    for (int i = 0; i < 64; ++i) {
      u32 w = xw[i];
      int e0 = (w >> 7) & 0xFF;
      int e1 = (w >> 23) & 0xFF;
      cnt += (e0 >= 90 && e0 <= 160) ? 1 : 0;
      cnt += (e1 >= 90 && e1 <= 160) ? 1 : 0;
    }
    *flag = (cnt >= 120) ? 1u : 0u;
  }
}

// ---------- prep_x: NCHW (fp32 or bf16) -> zero-padded NHWC bf16 [b][226][226][64] ----------
// u32-granular LDS transpose (conflict-free both phases, verified R3); 2 rows/block.
__global__ __launch_bounds__(256) void prep_x(const void* __restrict__ xv, u16* __restrict__ xb,
                                              const u32* __restrict__ flag) {
  __shared__ u32 tile32[2][64*33];   // [w_local][ic_pair], stride 33
  const bool isbf = (*flag != 0u);
  const int tid = threadIdx.x;
  int bid = blockIdx.x;
  const int chunk = bid & 3;         // 4 chunks of 64 input cols
  int rest = bid >> 2;
  const int hp0 = rest % 113;        // rows hp0 and hp0+113
  const int b = rest / 113;
  const int wt = chunk * 64;
  const int icp = tid >> 3;          // ic pair 0..31
  const int oct = tid & 7;           // w octet 0..7
  const int w = wt + oct*8;
  const int ic0 = icp*2;

  #pragma unroll
  for (int t = 0; t < 2; ++t) {
    const int hp = hp0 + t*113;
    const int h = hp - 1;
    const bool valid = (h >= 0) && (h < HH) && (w < WW);
    const size_t b0 = (((size_t)(b*ICN + ic0))*HH + h)*WW + w;
    const size_t b1 = (((size_t)(b*ICN + ic0+1))*HH + h)*WW + w;
    u16 a[8], c[8];
    if (isbf) {
      short8 v0 = {0,0,0,0,0,0,0,0}, v1 = {0,0,0,0,0,0,0,0};
      if (valid) {
        v0 = *(const short8*)((const u16*)xv + b0);
        v1 = *(const short8*)((const u16*)xv + b1);
      }
      #pragma unroll
      for (int s = 0; s < 8; ++s) { a[s] = (u16)v0[s]; c[s] = (u16)v1[s]; }
    } else {
      floatx4 f0={0,0,0,0}, f1={0,0,0,0}, f2={0,0,0,0}, f3={0,0,0,0};
      if (valid) {
        const float* p0 = (const float*)xv + b0;
        const float* p1 = (const float*)xv + b1;
        f0 = *(const floatx4*)p0; f1 = *(const floatx4*)(p0+4);
        f2 = *(const floatx4*)p1; f3 = *(const floatx4*)(p1+4);
      }
      #pragma unroll
      for (int s = 0; s < 4; ++s) {
        a[s] = f2bf(f0[s]); a[4+s] = f2bf(f1[s]);
        c[s] = f2bf(f2[s]); c[4+s] = f2bf(f3[s]);
      }
    }
    #pragma unroll
    for (int s = 0; s < 8; ++s)
      tile32[t][(oct*8 + s)*33 + icp] = (u32)a[s] | ((u32)c[s] << 16);
  }
  __syncthreads();
  #pragma unroll
  for (int t = 0; t < 2; ++t) {
    const int hp = hp0 + t*113;
    #pragma unroll
    for (int p = 0; p < 2; ++p) {
      int idx = p*256 + tid;
      int wl = idx >> 3;
      int icc = idx & 7;
      int wp = wt + 1 + wl;
      if (wp < WP) {
        u32 cc[4];
        #pragma unroll
        for (int j = 0; j < 4; ++j) cc[j] = tile32[t][wl*33 + icc*4 + j];
        short8 o;
        #pragma unroll
        for (int j = 0; j < 4; ++j) { o[2*j] = (short)(cc[j] & 0xFFFF); o[2*j+1] = (short)(cc[j] >> 16); }
        *(short8*)(xb + (((size_t)(b*HP) + hp)*WP + wp)*ICN + icc*8) = o;
      }
    }
    if (chunk == 0 && tid < 8) {     // left border column wp=0
      short8 z = {0,0,0,0,0,0,0,0};
      *(short8*)(xb + (((size_t)(b*HP) + hp)*WP)*ICN + tid*8) = z;
    }
  }
}

// ---------- prep_w: OIHW (fp32 or bf16) -> [oc][tap*64+ic] bf16 ----------
__global__ __launch_bounds__(256) void prep_w(const void* __restrict__ wv_, u16* __restrict__ wb,
                                              const u32* __restrict__ flag) {
  const bool isbf = (*flag != 0u);
  int o = blockIdx.x*256 + threadIdx.x;   // 0..73727
  int oc = o / 576;
  int k = o - oc*576;
  int tap = k >> 6;
  int ic = k & 63;
  int src = oc*576 + ic*9 + tap;
  wb[o] = isbf ? ((const u16*)wv_)[src] : f2bf(((const float*)wv_)[src]);
}

// ---------- fused conv3x3 + bias + min_oc + double tanh ----------
// Round-0 structure (one 2x40 tile per block). Changes vs round-0:
//   (a) A staged via global_load_lds width-16 (pre-swizzled per-lane GLOBAL source,
//       linear LDS dest = q*16; involution c = slot^(r&7) preserved on reads).
//       Removes staging VGPR round-trip + address VALU.
//   (b) B loaded per tap inside the fully-unrolled loop (no carried bcur/bnxt:
//       -16 regs; compiler hoists L2-hit loads within the 5-wave reg budget).
//   (c) __launch_bounds__(256,5): 5 blocks/CU (LDS 5x21504=105KB OK) to hide the
//       barrier-drain stall with an extra independent block.
// Tripwire: if WRITE_SIZE balloons above ~4 MB, (c) caused spills -> revert to 4.
__global__ __launch_bounds__(256, 5) void conv_min_kernel(
    const u16* __restrict__ xb, const u16* __restrict__ wb,
    const void* __restrict__ biasv, void* __restrict__ outv,
    const u32* __restrict__ flag)
{
  __shared__ __align__(16) char ldsA[A_BYTES];   // 168 rows x 128 B
  float* minbuf = (float*)ldsA;                  // aliased post-loop (barrier-fenced)

  const bool isbf = (*flag != 0u);
  const int tid = threadIdx.x;
  const int wv = tid >> 6;
  const int lane = tid & 63;
  const int m15 = lane & 15;
  const int quad = lane >> 4;

  int bid = blockIdx.x;
  const int wsel = bid % 6;
  int rest = bid / 6;
  const int h0 = (rest % 112) * 2;
  const int b = rest / 112;
  const int w0 = (wsel < 5) ? wsel*40 : 184;     // last chunk overlaps; stores idempotent

  // ---- stage A via async global->LDS. Chunk q = it*256 + tid:
  //   r = q>>3, slot = q&7; LDS byte addr = q*16 = r*128 + slot*16 (linear in lane order);
  //   source chunk c = slot ^ (r&7)  (involution -> reads keep round-0 swizzle).
  const char* srcb = (const char*)xb + 2*((((size_t)(b*HP) + h0)*WP)*ICN) + (size_t)w0*128;
  #pragma unroll
  for (int it = 0; it < 6; ++it) {
    if (it < 5 || wv == 0) {       // tail covers q=1280..1343 (wave 0 only)
      int q = it*256 + tid;
      int r = q >> 3;
      int slot = q & 7;
      int c = slot ^ (r & 7);
      int dyi = (r * 781) >> 15;   // r/42, exact for r < 168
      int wloc = r - dyi*42;
      int off = ((dyi*WP + wloc)*ICN + c*8) * 2;
      ASYNC16(srcb + off, ldsA + it*4096 + wv*1024);
    }
  }

  // ---- per-lane A-row bases: pixel p = mb*16 + m15 -> base = (p/40)*42 + p%40
  int arow[5];
  #pragma unroll
  for (int mb = 0; mb < 5; ++mb) {
    int p = mb*16 + m15;
    int ro = p / 40;
    arow[mb] = ro*42 + (p - ro*40);
  }

  const u16* bbase = wb + (wv*32 + m15)*576 + quad*8;

  floatx4 acc[5][2];
  #pragma unroll
  for (int mb = 0; mb < 5; ++mb) {
    acc[mb][0] = (floatx4){0.f,0.f,0.f,0.f};
    acc[mb][1] = (floatx4){0.f,0.f,0.f,0.f};
  }

  __syncthreads();                         // drains vmcnt -> A resident

  #pragma unroll
  for (int tap = 0; tap < 9; ++tap) {
    short8 bb[2][2];
    #pragma unroll
    for (int nb = 0; nb < 2; ++nb)
      #pragma unroll
      for (int ks = 0; ks < 2; ++ks)
        bb[nb][ks] = *(const short8*)(bbase + nb*16*576 + tap*64 + ks*32);
    const int dy = tap / 3;
    const int dx = tap - dy*3;
    const int rdelta = dy*42 + dx;
    #pragma unroll
    for (int ks = 0; ks < 2; ++ks) {
      const int csel = ks*4 + quad;
      short8 af[5];
      #pragma unroll
      for (int mb = 0; mb < 5; ++mb) {
        int row = arow[mb] + rdelta;
        af[mb] = *(const short8*)(ldsA + row*128 + ((csel ^ (row & 7))*16));
      }
      #pragma unroll
      for (int mb = 0; mb < 5; ++mb) {
        acc[mb][0] = __builtin_amdgcn_mfma_f32_16x16x32_bf16(af[mb], bb[0][ks], acc[mb][0], 0, 0, 0);
        acc[mb][1] = __builtin_amdgcn_mfma_f32_16x16x32_bf16(af[mb], bb[1][ks], acc[mb][1], 0, 0, 0);
      }
    }
  }
  __syncthreads();   // fence A reads before minbuf aliasing writes

  // ---- epilogue: +bias, min over oc, cross-lane/cross-wave min, tanh(tanh), store
  float bv0, bv1;
  if (isbf) {
    bv0 = __bfloat162float(((const __hip_bfloat16*)biasv)[wv*32 + m15]);
    bv1 = __bfloat162float(((const __hip_bfloat16*)biasv)[wv*32 + 16 + m15]);
  } else {
    bv0 = ((const float*)biasv)[wv*32 + m15];
    bv1 = ((const float*)biasv)[wv*32 + 16 + m15];
  }
  #pragma unroll
  for (int mb = 0; mb < 5; ++mb) {
    #pragma unroll
    for (int r = 0; r < 4; ++r) {
      float v = fminf(acc[mb][0][r] + bv0, acc[mb][1][r] + bv1);
      v = fminf(v, __shfl_xor(v, 1));
      v = fminf(v, __shfl_xor(v, 2));
      v = fminf(v, __shfl_xor(v, 4));
      v = fminf(v, __shfl_xor(v, 8));
      if (m15 == 0)
        minbuf[wv*MT + mb*16 + quad*4 + r] = v;   // pixel = mb*16 + quad*4 + r
    }
  }
  __syncthreads();
  if (tid < MT) {
    float v = fminf(fminf(minbuf[tid], minbuf[MT + tid]),
                    fminf(minbuf[2*MT + tid], minbuf[3*MT + tid]));
    float t = fast_tanh(fast_tanh(v));
    int ro = tid / 40;
    int co = tid - ro*40;
    size_t oi = ((size_t)(b*HH + h0 + ro))*WW + w0 + co;
    if (isbf) ((__hip_bfloat16*)outv)[oi] = __float2bfloat16(t);
    else      ((float*)outv)[oi] = t;
  }
}

extern "C" void kernel_launch(void* const* d_in, const int* in_sizes, int n_in,
                              void* d_out, int out_size, void* d_ws, size_t ws_size,
                              hipStream_t stream) {
  (void)in_sizes; (void)n_in; (void)out_size;
  if (ws_size < XB_BYTES + WB_BYTES + 16) return;

  const void* x  = d_in[0];
  const void* w  = d_in[1];
  const void* bias = d_in[2];
  u16* xb = (u16*)d_ws;
  u16* wb = (u16*)((char*)d_ws + XB_BYTES);
  u32* flag = (u32*)((char*)d_ws + XB_BYTES + WB_BYTES);

  detect_kernel<<<1, 64, 0, stream>>>((const u32*)x, flag);
  prep_x<<<BATCH*113*4, 256, 0, stream>>>(x, xb, flag);
  prep_w<<<288, 256, 0, stream>>>(w, wb, flag);
  conv_min_kernel<<<6*112*BATCH, 256, 0, stream>>>(xb, wb, bias, d_out, flag);
}

// Round 3
// 481.762 us; speedup vs baseline: 2.2214x; 1.0575x over previous
//
#include <hip/hip_runtime.h>
#include <hip/hip_bf16.h>

typedef __attribute__((ext_vector_type(8))) short short8;
typedef __attribute__((ext_vector_type(4))) float floatx4;
typedef unsigned short u16;
typedef unsigned int u32;

#define BATCH 16
#define HH 224
#define WW 224
#define ICN 64
#define OCN 128
#define HP 226
#define WP 226

// conv tile: 2 output rows x 40 cols per WG (6 w-chunks; last overlaps, stores idempotent)
#define MT 80
#define AR 168            // 4 padded input rows x 42 padded cols
#define AQ (AR*8)         // 1344 16-B chunks
#define A_BYTES (AR*128)  // 21504

#define NPX (BATCH*113*4)  // 7232 prep_x blocks; +288 prep_w tail blocks

#define XB_BYTES ((size_t)BATCH*HP*WP*ICN*2)   // 104,603,648
#define WB_BYTES ((size_t)OCN*ICN*9*2)         // 147,456

// async global->LDS, 16B per lane; LDS dest = wave-uniform base + lane*16
#define ASYNC16(g, l) __builtin_amdgcn_global_load_lds( \
    (const __attribute__((address_space(1))) void*)(g), \
    (__attribute__((address_space(3))) void*)(l), 16, 0, 0)

__device__ __forceinline__ u16 f2bf(float f) {
  __hip_bfloat16 h = __float2bfloat16(f);
  return *reinterpret_cast<u16*>(&h);
}

__device__ __forceinline__ float fast_tanh(float x) {
  float e = __expf(2.0f * x);    // x>>0 -> 1, x<<0 -> -1, inf-safe
  return 1.0f - 2.0f / (e + 1.0f);
}

// ---------- inline container-dtype detect (replaces detect_kernel launch) ----------
// bf16 containers: both u16 halves of words 0..63 have sane bf16 exponents.
// Wave-parallel: lane i checks word i&63; two 64-bit ballots + popcount.
// Uniform result per wave; every wave computes it (256-B L1-hit, ~free).
__device__ __forceinline__ bool detect_isbf(const u32* __restrict__ xw, int tid) {
  u32 w = xw[tid & 63];
  int e0 = (w >> 7) & 0xFF;
  int e1 = (w >> 23) & 0xFF;
  unsigned long long b0 = __ballot(e0 >= 90 && e0 <= 160);
  unsigned long long b1 = __ballot(e1 >= 90 && e1 <= 160);
  return (__popcll(b0) + __popcll(b1)) >= 120;
}

// ---------- prep_all: blocks [0,NPX) = prep_x, blocks [NPX,NPX+288) = prep_w ----------
// prep_x: NCHW (fp32 or bf16) -> zero-padded NHWC bf16 [b][226][226][64].
// u32-granular LDS transpose (conflict-free both phases, verified); 2 rows/block.
// prep_w: OIHW -> [oc][tap*64+ic] bf16.
__global__ __launch_bounds__(256) void prep_all(const void* __restrict__ xv,
                                                const void* __restrict__ wv_,
                                                u16* __restrict__ xb,
                                                u16* __restrict__ wb) {
  __shared__ u32 tile32[2][64*33];   // [w_local][ic_pair], stride 33
  const int tid = threadIdx.x;
  const bool isbf = detect_isbf((const u32*)xv, tid);
  int bid = blockIdx.x;

  if (bid >= NPX) {                  // ---- prep_w tail ----
    int o = (bid - NPX)*256 + tid;   // 0..73727
    int oc = o / 576;
    int k = o - oc*576;
    int tap = k >> 6;
    int ic = k & 63;
    int src = oc*576 + ic*9 + tap;
    wb[o] = isbf ? ((const u16*)wv_)[src] : f2bf(((const float*)wv_)[src]);
    return;
  }

  const int chunk = bid & 3;         // 4 chunks of 64 input cols
  int rest = bid >> 2;
  const int hp0 = rest % 113;        // rows hp0 and hp0+113
  const int b = rest / 113;
  const int wt = chunk * 64;
  const int icp = tid >> 3;          // ic pair 0..31
  const int oct = tid & 7;           // w octet 0..7
  const int w = wt + oct*8;
  const int ic0 = icp*2;

  #pragma unroll
  for (int t = 0; t < 2; ++t) {
    const int hp = hp0 + t*113;
    const int h = hp - 1;
    const bool valid = (h >= 0) && (h < HH) && (w < WW);
    const size_t b0 = (((size_t)(b*ICN + ic0))*HH + h)*WW + w;
    const size_t b1 = (((size_t)(b*ICN + ic0+1))*HH + h)*WW + w;
    u16 a[8], c[8];
    if (isbf) {
      short8 v0 = {0,0,0,0,0,0,0,0}, v1 = {0,0,0,0,0,0,0,0};
      if (valid) {
        v0 = *(const short8*)((const u16*)xv + b0);
        v1 = *(const short8*)((const u16*)xv + b1);
      }
      #pragma unroll
      for (int s = 0; s < 8; ++s) { a[s] = (u16)v0[s]; c[s] = (u16)v1[s]; }
    } else {
      floatx4 f0={0,0,0,0}, f1={0,0,0,0}, f2={0,0,0,0}, f3={0,0,0,0};
      if (valid) {
        const float* p0 = (const float*)xv + b0;
        const float* p1 = (const float*)xv + b1;
        f0 = *(const floatx4*)p0; f1 = *(const floatx4*)(p0+4);
        f2 = *(const floatx4*)p1; f3 = *(const floatx4*)(p1+4);
      }
      #pragma unroll
      for (int s = 0; s < 4; ++s) {
        a[s] = f2bf(f0[s]); a[4+s] = f2bf(f1[s]);
        c[s] = f2bf(f2[s]); c[4+s] = f2bf(f3[s]);
      }
    }
    #pragma unroll
    for (int s = 0; s < 8; ++s)
      tile32[t][(oct*8 + s)*33 + icp] = (u32)a[s] | ((u32)c[s] << 16);
  }
  __syncthreads();
  #pragma unroll
  for (int t = 0; t < 2; ++t) {
    const int hp = hp0 + t*113;
    #pragma unroll
    for (int p = 0; p < 2; ++p) {
      int idx = p*256 + tid;
      int wl = idx >> 3;
      int icc = idx & 7;
      int wp = wt + 1 + wl;
      if (wp < WP) {
        u32 cc[4];
        #pragma unroll
        for (int j = 0; j < 4; ++j) cc[j] = tile32[t][wl*33 + icc*4 + j];
        short8 o;
        #pragma unroll
        for (int j = 0; j < 4; ++j) { o[2*j] = (short)(cc[j] & 0xFFFF); o[2*j+1] = (short)(cc[j] >> 16); }
        *(short8*)(xb + (((size_t)(b*HP) + hp)*WP + wp)*ICN + icc*8) = o;
      }
    }
    if (chunk == 0 && tid < 8) {     // left border column wp=0
      short8 z = {0,0,0,0,0,0,0,0};
      *(short8*)(xb + (((size_t)(b*HP) + hp)*WP)*ICN + tid*8) = z;
    }
  }
}

// ---------- fused conv3x3 + bias + min_oc + double tanh ----------
// Round-0 tap loop (explicit bcur/bnxt B-prefetch: round-2 showed per-tap B loads
// expose ~200cy L2 latency per tap, +18us) + ASYNC16 staging (round-2 verified:
// pre-swizzled per-lane GLOBAL source c = slot^(r&7), linear LDS dest = q*16;
// involution preserved on reads). isbf detected inline from x (no flag dependency).
__global__ __launch_bounds__(256, 4) void conv_min_kernel(
    const u16* __restrict__ xb, const u16* __restrict__ wb,
    const void* __restrict__ biasv, void* __restrict__ outv,
    const void* __restrict__ xv)
{
  __shared__ __align__(16) char ldsA[A_BYTES];   // 168 rows x 128 B
  float* minbuf = (float*)ldsA;                  // aliased post-loop (barrier-fenced)

  const int tid = threadIdx.x;
  const bool isbf = detect_isbf((const u32*)xv, tid);
  const int wv = tid >> 6;
  const int lane = tid & 63;
  const int m15 = lane & 15;
  const int quad = lane >> 4;

  int bid = blockIdx.x;
  const int wsel = bid % 6;
  int rest = bid / 6;
  const int h0 = (rest % 112) * 2;
  const int b = rest / 112;
  const int w0 = (wsel < 5) ? wsel*40 : 184;     // last chunk overlaps; stores idempotent

  // ---- stage A via async global->LDS. Chunk q = it*256 + tid:
  //   r = q>>3, slot = q&7; LDS byte addr = q*16 (linear); src chunk c = slot^(r&7).
  const char* srcb = (const char*)xb + 2*((((size_t)(b*HP) + h0)*WP)*ICN) + (size_t)w0*128;
  #pragma unroll
  for (int it = 0; it < 6; ++it) {
    if (it < 5 || wv == 0) {       // tail covers q=1280..1343 (wave 0 only)
      int q = it*256 + tid;
      int r = q >> 3;
      int slot = q & 7;
      int c = slot ^ (r & 7);
      int dyi = (r * 781) >> 15;   // r/42, exact for r < 168
      int wloc = r - dyi*42;
      int off = ((dyi*WP + wloc)*ICN + c*8) * 2;
      ASYNC16(srcb + off, ldsA + it*4096 + wv*1024);
    }
  }

  // ---- per-lane A-row bases: pixel p = mb*16 + m15 -> base = (p/40)*42 + p%40
  int arow[5];
  #pragma unroll
  for (int mb = 0; mb < 5; ++mb) {
    int p = mb*16 + m15;
    int ro = p / 40;
    arow[mb] = ro*42 + (p - ro*40);
  }

  // ---- per-lane B: row oc = wv*32 + nb*16 + m15, k-chunk = ks*4 + quad
  const u16* bbase = wb + (wv*32 + m15)*576 + quad*8;
  short8 bcur[2][2];
  #pragma unroll
  for (int nb = 0; nb < 2; ++nb)
    #pragma unroll
    for (int ks = 0; ks < 2; ++ks)
      bcur[nb][ks] = *(const short8*)(bbase + nb*16*576 + ks*32);

  floatx4 acc[5][2];
  #pragma unroll
  for (int mb = 0; mb < 5; ++mb) {
    acc[mb][0] = (floatx4){0.f,0.f,0.f,0.f};
    acc[mb][1] = (floatx4){0.f,0.f,0.f,0.f};
  }

  __syncthreads();                         // drains vmcnt -> A resident

  #pragma unroll
  for (int tap = 0; tap < 9; ++tap) {
    short8 bnxt[2][2];
    if (tap < 8) {                         // prefetch next tap's B frags (L2-hit)
      #pragma unroll
      for (int nb = 0; nb < 2; ++nb)
        #pragma unroll
        for (int ks = 0; ks < 2; ++ks)
          bnxt[nb][ks] = *(const short8*)(bbase + nb*16*576 + (tap+1)*64 + ks*32);
    }
    const int dy = tap / 3;
    const int dx = tap - dy*3;
    const int rdelta = dy*42 + dx;
    #pragma unroll
    for (int ks = 0; ks < 2; ++ks) {
      const int csel = ks*4 + quad;
      short8 af[5];
      #pragma unroll
      for (int mb = 0; mb < 5; ++mb) {
        int row = arow[mb] + rdelta;
        af[mb] = *(const short8*)(ldsA + row*128 + ((csel ^ (row & 7))*16));
      }
      #pragma unroll
      for (int mb = 0; mb < 5; ++mb) {
        acc[mb][0] = __builtin_amdgcn_mfma_f32_16x16x32_bf16(af[mb], bcur[0][ks], acc[mb][0], 0, 0, 0);
        acc[mb][1] = __builtin_amdgcn_mfma_f32_16x16x32_bf16(af[mb], bcur[1][ks], acc[mb][1], 0, 0, 0);
      }
    }
    if (tap < 8) {
      #pragma unroll
      for (int nb = 0; nb < 2; ++nb)
        #pragma unroll
        for (int ks = 0; ks < 2; ++ks)
          bcur[nb][ks] = bnxt[nb][ks];
    }
  }
  __syncthreads();   // fence A reads before minbuf aliasing writes

  // ---- epilogue: +bias, min over oc, cross-lane/cross-wave min, tanh(tanh), store
  float bv0, bv1;
  if (isbf) {
    bv0 = __bfloat162float(((const __hip_bfloat16*)biasv)[wv*32 + m15]);
    bv1 = __bfloat162float(((const __hip_bfloat16*)biasv)[wv*32 + 16 + m15]);
  } else {
    bv0 = ((const float*)biasv)[wv*32 + m15];
    bv1 = ((const float*)biasv)[wv*32 + 16 + m15];
  }
  #pragma unroll
  for (int mb = 0; mb < 5; ++mb) {
    #pragma unroll
    for (int r = 0; r < 4; ++r) {
      float v = fminf(acc[mb][0][r] + bv0, acc[mb][1][r] + bv1);
      v = fminf(v, __shfl_xor(v, 1));
      v = fminf(v, __shfl_xor(v, 2));
      v = fminf(v, __shfl_xor(v, 4));
      v = fminf(v, __shfl_xor(v, 8));
      if (m15 == 0)
        minbuf[wv*MT + mb*16 + quad*4 + r] = v;   // pixel = mb*16 + quad*4 + r
    }
  }
  __syncthreads();
  if (tid < MT) {
    float v = fminf(fminf(minbuf[tid], minbuf[MT + tid]),
                    fminf(minbuf[2*MT + tid], minbuf[3*MT + tid]));
    float t = fast_tanh(fast_tanh(v));
    int ro = tid / 40;
    int co = tid - ro*40;
    size_t oi = ((size_t)(b*HH + h0 + ro))*WW + w0 + co;
    if (isbf) ((__hip_bfloat16*)outv)[oi] = __float2bfloat16(t);
    else      ((float*)outv)[oi] = t;
  }
}

extern "C" void kernel_launch(void* const* d_in, const int* in_sizes, int n_in,
                              void* d_out, int out_size, void* d_ws, size_t ws_size,
                              hipStream_t stream) {
  (void)in_sizes; (void)n_in; (void)out_size;
  if (ws_size < XB_BYTES + WB_BYTES + 16) return;

  const void* x  = d_in[0];
  const void* w  = d_in[1];
  const void* bias = d_in[2];
  u16* xb = (u16*)d_ws;
  u16* wb = (u16*)((char*)d_ws + XB_BYTES);

  prep_all<<<NPX + 288, 256, 0, stream>>>(x, w, xb, wb);
  conv_min_kernel<<<6*112*BATCH, 256, 0, stream>>>(xb, wb, bias, d_out, x);
}